// Round 5
// baseline (713.058 us; speedup 1.0000x reference)
//
#include <hip/hip_runtime.h>

constexpr int T = 168;
constexpr int P = 16;
constexpr int H = 24;
constexpr int RPW = 4;   // rows per wave

typedef float v2f __attribute__((ext_vector_type(2)));

__device__ __forceinline__ v2f mk2(float a, float b) { v2f r; r[0] = a; r[1] = b; return r; }
__device__ __forceinline__ v2f bc2(float a)          { v2f r; r[0] = a; r[1] = a; return r; }
// 2 fp32 FMAs in one instruction (v_pk_fma_f32).
__device__ __forceinline__ v2f pkfma(v2f a, v2f b, v2f c) {
    return __builtin_elementwise_fma(a, b, c);
}

__device__ __forceinline__ float rcp_f(float x) { return __builtin_amdgcn_rcpf(x); }
__device__ __forceinline__ float sigm_f(float x) { return rcp_f(1.f + __expf(-x)); }
// tanh(x) = 2*sigmoid(2x) - 1
__device__ __forceinline__ float tanh_fast(float x) {
    return fmaf(2.f, rcp_f(1.f + __expf(-2.f * x)), -1.f);
}

#define KEEP2(v) asm volatile("" : "+v"(v))
// Intra-wave LDS write->read ordering + compiler reorder fence.
#define LDS_SYNC() asm volatile("s_waitcnt lgkmcnt(0)" ::: "memory")

// 4 packed FMAs: acc += v4.{x,y,z,w} * w[b..b+3]
#define PK4(acc_, v4_, w_, b_) do {                       \
    acc_ = pkfma(bc2((v4_).x), (w_)[(b_)],     acc_);     \
    acc_ = pkfma(bc2((v4_).y), (w_)[(b_) + 1], acc_);     \
    acc_ = pkfma(bc2((v4_).z), (w_)[(b_) + 2], acc_);     \
    acc_ = pkfma(bc2((v4_).w), (w_)[(b_) + 3], acc_); } while (0)

// Gate nonlinearity + state update + h store. tdst==nullptr folds away.
__device__ __forceinline__ void act_store(v2f g, int lane, int half,
                                          float& c, float* hdst, float* tdst)
{
    float a0 = sigm_f(g[0]);                        // i (half0) | f (half1)
    float px = (half == 0) ? g[1] + g[1] : g[1];
    float sv = sigm_f(px);
    float a1 = (half == 0) ? sv + sv - 1.f : sv;    // tanh(g) | o
    float fa = __shfl(a0, lane + 24);
    float oa = __shfl(a1, lane + 24);
    c = fmaf(fa, c, a0 * a1);
    float hv = oa * tanh_fast(c);
    if (tdst) {
        float th = tanh_fast(hv);
        if (lane < H) { hdst[lane] = hv; tdst[lane] = th; }
    } else {
        if (lane < H) hdst[lane] = hv;
    }
}

// R11 (resubmit after infra failure): attack in-phase stalling with in-wave
// ILP. Evidence (R10): VALUBusy 46%, >50% no-issue despite 2 resident waves —
// identical waves launched together stall on the same serial chains
// simultaneously, so TLP covers nothing.
// Change: 4 rows/wave (8 independent gate chains + 8 activation chains per
// step) so the COMPILER interleaves independent work into every stall window.
// Weights are row-invariant -> register cost only grows by accs/temps
// (~230-250 total), which demands waves_per_eu(1,1): cap 512, spill-proof
// (R9's 2.3x regression was this body under a 2-wave register cap).
// Grid: 1024 blocks = exactly 1 wave/SIMD — what we effectively had anyway.
// Keeps: R8/R10 layer pipeline (L1[t+1] || L2[t], ONE lgkmcnt(0) drain/step,
// t1 double buffer), R4 lane layout (lane u: gates {i,g}; lane 24+u: {f,o}).
__global__ __attribute__((amdgpu_flat_work_group_size(64, 64),
                          amdgpu_waves_per_eu(1, 1)))
void lstm2_r4w(const float* __restrict__ x,
               const float* __restrict__ Wih1, const float* __restrict__ Whh1,
               const float* __restrict__ bih1, const float* __restrict__ bhh1,
               const float* __restrict__ Wih2, const float* __restrict__ Whh2,
               const float* __restrict__ bih2, const float* __restrict__ bhh2,
               const float* __restrict__ W1, const float* __restrict__ b1,
               const float* __restrict__ W2, const float* __restrict__ b2,
               float* __restrict__ out)
{
    const int lane = threadIdx.x;                 // 0..63
    const int s    = (lane < 48) ? lane : 47;     // clamp idle lanes
    const int u    = s % H;                       // unit 0..23
    const int half = s / H;                       // 0: {i,g}, 1: {f,o}
    const int q0   = half * H + u;                // i or f gate row
    const int q1   = (2 + half) * H + u;          // g or o gate row
    const int row0 = blockIdx.x * RPW;

    // ---- weights as packed pairs: 88 v2f = 176 floats (row-invariant) ----
    v2f wx[P];   // Wih1 {q0,q1}
    v2f wh[H];   // Whh1 {q0,q1}
    v2f vx[H];   // Wih2 {q0,q1}
    v2f vh[H];   // Whh2 {q0,q1}
    #pragma unroll
    for (int k = 0; k < P; ++k) wx[k] = mk2(Wih1[q0 * P + k], Wih1[q1 * P + k]);
    #pragma unroll
    for (int k = 0; k < H; ++k) wh[k] = mk2(Whh1[q0 * H + k], Whh1[q1 * H + k]);
    #pragma unroll
    for (int k = 0; k < H; ++k) vx[k] = mk2(Wih2[q0 * H + k], Wih2[q1 * H + k]);
    #pragma unroll
    for (int k = 0; k < H; ++k) vh[k] = mk2(Whh2[q0 * H + k], Whh2[q1 * H + k]);
    v2f bias1 = mk2(bih1[q0] + bhh1[q0], bih1[q1] + bhh1[q1]);
    v2f bias2 = mk2(bih2[q0] + bhh2[q0], bih2[q1] + bhh2[q1]);

    #pragma unroll
    for (int k = 0; k < P; ++k) KEEP2(wx[k]);
    #pragma unroll
    for (int k = 0; k < H; ++k) { KEEP2(wh[k]); KEEP2(vx[k]); KEEP2(vh[k]); }
    KEEP2(bias1); KEEP2(bias2);

    __shared__ __align__(16) float h1s[RPW][32];       // layer-1 h, per row
    __shared__ __align__(16) float t1s[2][RPW][32];    // [buf][row] tanh(h1)
    __shared__ __align__(16) float h2s[RPW][32];       // layer-2 h

    if (lane < H) {
        #pragma unroll
        for (int r = 0; r < RPW; ++r) {
            h1s[r][lane] = 0.f; h2s[r][lane] = 0.f;
            t1s[0][r][lane] = 0.f; t1s[1][r][lane] = 0.f;
        }
    }
    LDS_SYNC();

    const float* xp[RPW];                          // wave-uniform (SGPR)
    #pragma unroll
    for (int r = 0; r < RPW; ++r) xp[r] = x + (size_t)(row0 + r) * T * P;

    float c1[RPW] = {0.f, 0.f, 0.f, 0.f};
    float c2[RPW] = {0.f, 0.f, 0.f, 0.f};

    // ---- prologue: L1 step 0 (h1 = 0 -> x-part + bias only) ----
    #pragma unroll
    for (int r = 0; r < RPW; ++r) {
        v2f g = bias1;
        #pragma unroll
        for (int j = 0; j < P / 4; ++j) {
            float4 v = ((const float4*)xp[r])[j];
            PK4(g, v, wx, 4 * j);
        }
        act_store(g, lane, half, c1[r], h1s[r], t1s[0][r]);
    }
    LDS_SYNC();

    int tb = 0;
    for (int t = 0; t < T - 1; ++t) {
        v2f g[RPW], f[RPW];

        // ===== L1 gates step t+1: x-part (global loads issue first) =====
        #pragma unroll
        for (int r = 0; r < RPW; ++r) {
            g[r] = bias1;
            const float4* x4 = (const float4*)(xp[r] + (t + 1) * P);
            #pragma unroll
            for (int j = 0; j < P / 4; ++j) {
                float4 v = x4[j];
                PK4(g[r], v, wx, 4 * j);
            }
        }
        // ===== L1 h-part (4 independent chains) =====
        #pragma unroll
        for (int r = 0; r < RPW; ++r) {
            #pragma unroll
            for (int k = 0; k < H / 4; ++k) {
                float4 hv = ((const float4*)h1s[r])[k];
                PK4(g[r], hv, wh, 4 * k);
            }
        }
        // ===== L2 gates step t: t-part + h-part (4 independent chains) =====
        #pragma unroll
        for (int r = 0; r < RPW; ++r) {
            f[r] = bias2;
            #pragma unroll
            for (int k = 0; k < H / 4; ++k) {
                float4 tv = ((const float4*)t1s[tb][r])[k];
                PK4(f[r], tv, vx, 4 * k);
            }
            #pragma unroll
            for (int k = 0; k < H / 4; ++k) {
                float4 hv = ((const float4*)h2s[r])[k];
                PK4(f[r], hv, vh, 4 * k);
            }
        }

        // ===== activations: 8 independent chains, then ONE drain =====
        #pragma unroll
        for (int r = 0; r < RPW; ++r)
            act_store(g[r], lane, half, c1[r], h1s[r], t1s[tb ^ 1][r]);
        #pragma unroll
        for (int r = 0; r < RPW; ++r)
            act_store(f[r], lane, half, c2[r], h2s[r], nullptr);
        LDS_SYNC();
        tb ^= 1;
    }

    // ---- epilogue: L2 step T-1 ----
    #pragma unroll
    for (int r = 0; r < RPW; ++r) {
        v2f f = bias2;
        #pragma unroll
        for (int k = 0; k < H / 4; ++k) {
            float4 tv = ((const float4*)t1s[tb][r])[k];
            PK4(f, tv, vx, 4 * k);
        }
        #pragma unroll
        for (int k = 0; k < H / 4; ++k) {
            float4 hv = ((const float4*)h2s[r])[k];
            PK4(f, hv, vh, 4 * k);
        }
        act_store(f, lane, half, c2[r], h2s[r], nullptr);
    }
    LDS_SYNC();

    // ---- head: tanh -> fc1(16, relu) -> fc2(24), all rows ----
    if (lane < H) {
        #pragma unroll
        for (int r = 0; r < RPW; ++r) t1s[0][r][lane] = tanh_fast(h2s[r][lane]);
    }
    LDS_SYNC();
    if (lane < 16) {
        float acc[RPW];
        #pragma unroll
        for (int r = 0; r < RPW; ++r) acc[r] = b1[lane];
        #pragma unroll
        for (int j = 0; j < H; ++j) {
            float w = W1[lane * H + j];
            #pragma unroll
            for (int r = 0; r < RPW; ++r) acc[r] = fmaf(t1s[0][r][j], w, acc[r]);
        }
        #pragma unroll
        for (int r = 0; r < RPW; ++r) h1s[r][lane] = fmaxf(acc[r], 0.f);
    }
    LDS_SYNC();
    if (lane < H) {
        float acc[RPW];
        #pragma unroll
        for (int r = 0; r < RPW; ++r) acc[r] = b2[lane];
        #pragma unroll
        for (int j = 0; j < 16; ++j) {
            float w = W2[lane * 16 + j];
            #pragma unroll
            for (int r = 0; r < RPW; ++r) acc[r] = fmaf(h1s[r][j], w, acc[r]);
        }
        #pragma unroll
        for (int r = 0; r < RPW; ++r)
            out[(size_t)(row0 + r) * H + lane] = acc[r];
    }
}

extern "C" void kernel_launch(void* const* d_in, const int* in_sizes, int n_in,
                              void* d_out, int out_size, void* d_ws, size_t ws_size,
                              hipStream_t stream)
{
    const float* x    = (const float*)d_in[0];
    const float* Wih1 = (const float*)d_in[1];
    const float* Whh1 = (const float*)d_in[2];
    const float* bih1 = (const float*)d_in[3];
    const float* bhh1 = (const float*)d_in[4];
    const float* Wih2 = (const float*)d_in[5];
    const float* Whh2 = (const float*)d_in[6];
    const float* bih2 = (const float*)d_in[7];
    const float* bhh2 = (const float*)d_in[8];
    const float* W1   = (const float*)d_in[9];
    const float* b1   = (const float*)d_in[10];
    const float* W2   = (const float*)d_in[11];
    const float* b2   = (const float*)d_in[12];
    float* out = (float*)d_out;

    const int B = in_sizes[0] / (T * P);             // 4096
    hipLaunchKernelGGL(lstm2_r4w, dim3(B / RPW), dim3(64), 0, stream,
                       x, Wih1, Whh1, bih1, bhh1, Wih2, Whh2, bih2, bhh2,
                       W1, b1, W2, b2, out);
}

// Round 6
// 441.092 us; speedup vs baseline: 1.6166x; 1.6166x over previous
//
#include <hip/hip_runtime.h>

constexpr int T = 168;
constexpr int P = 16;
constexpr int H = 24;

typedef float v2f __attribute__((ext_vector_type(2)));

__device__ __forceinline__ v2f mk2(float a, float b) { v2f r; r[0] = a; r[1] = b; return r; }
__device__ __forceinline__ v2f bc2(float a)          { v2f r; r[0] = a; r[1] = a; return r; }
// 2 fp32 FMAs in one instruction (v_pk_fma_f32).
__device__ __forceinline__ v2f pkfma(v2f a, v2f b, v2f c) {
    return __builtin_elementwise_fma(a, b, c);
}

__device__ __forceinline__ float rcp_f(float x) { return __builtin_amdgcn_rcpf(x); }
__device__ __forceinline__ float sigm_f(float x) { return rcp_f(1.f + __expf(-x)); }
// tanh(x) = 2*sigmoid(2x) - 1
__device__ __forceinline__ float tanh_fast(float x) {
    return fmaf(2.f, rcp_f(1.f + __expf(-2.f * x)), -1.f);
}

#define KEEP2(v) asm volatile("" : "+v"(v))
// Intra-wave LDS write->read ordering + compiler reorder fence.
#define LDS_SYNC() asm volatile("s_waitcnt lgkmcnt(0)" ::: "memory")

// 4 packed FMAs: acc += v4.{x,y,z,w} * w[b..b+3]
#define PK4(acc_, v4_, w_, b_) do {                       \
    acc_ = pkfma(bc2((v4_).x), (w_)[(b_)],     acc_);     \
    acc_ = pkfma(bc2((v4_).y), (w_)[(b_) + 1], acc_);     \
    acc_ = pkfma(bc2((v4_).z), (w_)[(b_) + 2], acc_);     \
    acc_ = pkfma(bc2((v4_).w), (w_)[(b_) + 3], acc_); } while (0)

// Gate nonlinearity + state update + h store. tdst==nullptr folds away.
__device__ __forceinline__ void act_store(v2f g, int lane, int half,
                                          float& c, float* hdst, float* tdst)
{
    float a0 = sigm_f(g[0]);                        // i (half0) | f (half1)
    float px = (half == 0) ? g[1] + g[1] : g[1];
    float sv = sigm_f(px);
    float a1 = (half == 0) ? sv + sv - 1.f : sv;    // tanh(g) | o
    float fa = __shfl(a0, lane + 24);
    float oa = __shfl(a1, lane + 24);
    c = fmaf(fa, c, a0 * a1);
    float hv = oa * tanh_fast(c);
    if (tdst) {
        float th = tanh_fast(hv);
        if (lane < H) { hdst[lane] = hv; tdst[lane] = th; }
    } else {
        if (lane < H) hdst[lane] = hv;
    }
}

// R12: wave-specialized layer split. Measured ladder: R4 (128 VGPR, 2 w/SIMD,
// VALUBusy 23%) = 389us; R10/R11 (164/236 VGPR) dropped residency to ~1/SIMD
// (occ 11.5%) and LOST despite 1.36-1.56x per-wave ILP gains. Crossing 128
// VGPRs halves residency; the 176-reg dual-layer weight set is the floor.
// Fix: per block, wave0 = layer-1 only, wave1 = layer-2 only. Both paths
// share ONE v2f w[48] array (96 regs) -> allocator never holds both layers'
// weights; peak live ~120 <= 128, pinned by waves_per_eu(4,4).
// 2048 blocks x 2 waves = 4096 waves = 4/SIMD (2x R4's residency) of TWO
// DIFFERENT instruction streams (de-phased stalls). Cross-wave pipeline:
// wave0 produces t1[t] into LDS buf t&1; wave1 consumes t1[t-1] from buf
// (t-1)&1; ONE lgkmcnt(0)+s_barrier per step closes the race (WAR on buf
// reuse is covered: reader's lgkmcnt(0) retires its ds_reads pre-barrier).
// Lane layout per wave unchanged: lane u: gates {i,g}; lane 24+u: {f,o};
// 2 rows (A,B) per block.
__global__ __attribute__((amdgpu_flat_work_group_size(128, 128),
                          amdgpu_waves_per_eu(4, 4)))
void lstm2_split(const float* __restrict__ x,
                 const float* __restrict__ Wih1, const float* __restrict__ Whh1,
                 const float* __restrict__ bih1, const float* __restrict__ bhh1,
                 const float* __restrict__ Wih2, const float* __restrict__ Whh2,
                 const float* __restrict__ bih2, const float* __restrict__ bhh2,
                 const float* __restrict__ W1, const float* __restrict__ b1,
                 const float* __restrict__ W2, const float* __restrict__ b2,
                 float* __restrict__ out)
{
    const int tid  = threadIdx.x;
    const int wid  = tid >> 6;                    // 0: L1 wave, 1: L2 wave
    const int lane = tid & 63;
    const int s    = (lane < 48) ? lane : 47;     // clamp idle lanes
    const int u    = s % H;                       // unit 0..23
    const int half = s / H;                       // 0: {i,g}, 1: {f,o}
    const int q0   = half * H + u;                // i or f gate row
    const int q1   = (2 + half) * H + u;          // g or o gate row
    const int rowA = blockIdx.x * 2;
    const int rowB = rowA + 1;

    // ---- unified weight storage: 48 v2f = 96 VGPRs, per-wave meaning ----
    // wave0: w[0..15] = Wih1 pairs, w[16..39] = Whh1 pairs, w[40..47] zero
    // wave1: w[0..23] = Wih2 pairs, w[24..47] = Whh2 pairs
    v2f w[48];
    v2f bias;
    if (wid == 0) {
        #pragma unroll
        for (int k = 0; k < P; ++k) w[k]     = mk2(Wih1[q0 * P + k], Wih1[q1 * P + k]);
        #pragma unroll
        for (int k = 0; k < H; ++k) w[P + k] = mk2(Whh1[q0 * H + k], Whh1[q1 * H + k]);
        #pragma unroll
        for (int k = P + H; k < 48; ++k) w[k] = bc2(0.f);
        bias = mk2(bih1[q0] + bhh1[q0], bih1[q1] + bhh1[q1]);
    } else {
        #pragma unroll
        for (int k = 0; k < H; ++k) w[k]     = mk2(Wih2[q0 * H + k], Wih2[q1 * H + k]);
        #pragma unroll
        for (int k = 0; k < H; ++k) w[H + k] = mk2(Whh2[q0 * H + k], Whh2[q1 * H + k]);
        bias = mk2(bih2[q0] + bhh2[q0], bih2[q1] + bhh2[q1]);
    }
    #pragma unroll
    for (int k = 0; k < 48; ++k) KEEP2(w[k]);
    KEEP2(bias);

    __shared__ __align__(16) float h1s[2][32];       // L1 h (wave0-private)
    __shared__ __align__(16) float t1s[2][2][32];    // [buf][row] tanh(h1), shared
    __shared__ __align__(16) float h2s[2][32];       // L2 h (wave1-private)

    const float* __restrict__ xA = x + (size_t)rowA * T * P;  // wave-uniform
    const float* __restrict__ xB = x + (size_t)rowB * T * P;

    float cA = 0.f, cB = 0.f;     // c1 (wave0) / c2 (wave1)

    // ---- superstep 0: wave0 does L1 step 0 (h1=0 -> x-part only);
    //      wave1 zero-inits its h2 state. h1s/t1s need no init (written
    //      before first read). ----
    if (wid == 0) {
        v2f gA = bias, gB = bias;
        #pragma unroll
        for (int j = 0; j < P / 4; ++j) {
            float4 va = ((const float4*)xA)[j];
            float4 vb = ((const float4*)xB)[j];
            PK4(gA, va, w, 4 * j);
            PK4(gB, vb, w, 4 * j);
        }
        act_store(gA, lane, half, cA, h1s[0], t1s[0][0]);
        act_store(gB, lane, half, cB, h1s[1], t1s[0][1]);
    } else {
        if (lane < H) { h2s[0][lane] = 0.f; h2s[1][lane] = 0.f; }
    }
    LDS_SYNC();
    __builtin_amdgcn_s_barrier();

    // ---- supersteps 1..T-1: wave0 = L1 step t, wave1 = L2 step t-1 ----
    for (int t = 1; t < T; ++t) {
        if (wid == 0) {
            v2f gA = bias, gB = bias;
            const float4* xa4 = (const float4*)(xA + t * P);
            const float4* xb4 = (const float4*)(xB + t * P);
            #pragma unroll
            for (int j = 0; j < P / 4; ++j) {
                float4 va = xa4[j];
                float4 vb = xb4[j];
                PK4(gA, va, w, 4 * j);
                PK4(gB, vb, w, 4 * j);
            }
            #pragma unroll
            for (int k = 0; k < H / 4; ++k) {
                float4 ha = ((const float4*)h1s[0])[k];
                float4 hb = ((const float4*)h1s[1])[k];
                PK4(gA, ha, w, P + 4 * k);
                PK4(gB, hb, w, P + 4 * k);
            }
            act_store(gA, lane, half, cA, h1s[0], t1s[t & 1][0]);
            act_store(gB, lane, half, cB, h1s[1], t1s[t & 1][1]);
        } else {
            v2f fA = bias, fB = bias;
            const float* t1a = t1s[(t - 1) & 1][0];
            const float* t1b = t1s[(t - 1) & 1][1];
            #pragma unroll
            for (int k = 0; k < H / 4; ++k) {
                float4 ta  = ((const float4*)t1a)[k];
                float4 tb4 = ((const float4*)t1b)[k];
                PK4(fA, ta,  w, 4 * k);
                PK4(fB, tb4, w, 4 * k);
            }
            #pragma unroll
            for (int k = 0; k < H / 4; ++k) {
                float4 ha = ((const float4*)h2s[0])[k];
                float4 hb = ((const float4*)h2s[1])[k];
                PK4(fA, ha, w, H + 4 * k);
                PK4(fB, hb, w, H + 4 * k);
            }
            act_store(fA, lane, half, cA, h2s[0], nullptr);
            act_store(fB, lane, half, cB, h2s[1], nullptr);
        }
        LDS_SYNC();
        __builtin_amdgcn_s_barrier();
    }

    // ---- tail (wave1 only): L2 step T-1, then the head. wave0 is done
    //      (its last t1 write was drained+barriered) and just exits. ----
    if (wid == 1) {
        v2f fA = bias, fB = bias;
        const float* t1a = t1s[(T - 1) & 1][0];
        const float* t1b = t1s[(T - 1) & 1][1];
        #pragma unroll
        for (int k = 0; k < H / 4; ++k) {
            float4 ta  = ((const float4*)t1a)[k];
            float4 tb4 = ((const float4*)t1b)[k];
            PK4(fA, ta,  w, 4 * k);
            PK4(fB, tb4, w, 4 * k);
        }
        #pragma unroll
        for (int k = 0; k < H / 4; ++k) {
            float4 ha = ((const float4*)h2s[0])[k];
            float4 hb = ((const float4*)h2s[1])[k];
            PK4(fA, ha, w, H + 4 * k);
            PK4(fB, hb, w, H + 4 * k);
        }
        act_store(fA, lane, half, cA, h2s[0], nullptr);
        act_store(fB, lane, half, cB, h2s[1], nullptr);
        LDS_SYNC();

        // head: tanh -> fc1(16, relu) -> fc2(24), both rows (intra-wave)
        if (lane < H) {
            t1s[0][0][lane] = tanh_fast(h2s[0][lane]);
            t1s[0][1][lane] = tanh_fast(h2s[1][lane]);
        }
        LDS_SYNC();
        if (lane < 16) {
            float accA = b1[lane], accB = b1[lane];
            #pragma unroll
            for (int j = 0; j < H; ++j) {
                float wv = W1[lane * H + j];
                accA = fmaf(t1s[0][0][j], wv, accA);
                accB = fmaf(t1s[0][1][j], wv, accB);
            }
            h1s[0][lane] = fmaxf(accA, 0.f);
            h1s[1][lane] = fmaxf(accB, 0.f);
        }
        LDS_SYNC();
        if (lane < H) {
            float accA = b2[lane], accB = b2[lane];
            #pragma unroll
            for (int j = 0; j < 16; ++j) {
                float wv = W2[lane * 16 + j];
                accA = fmaf(h1s[0][j], wv, accA);
                accB = fmaf(h1s[1][j], wv, accB);
            }
            out[(size_t)rowA * H + lane] = accA;
            out[(size_t)rowB * H + lane] = accB;
        }
    }
}

extern "C" void kernel_launch(void* const* d_in, const int* in_sizes, int n_in,
                              void* d_out, int out_size, void* d_ws, size_t ws_size,
                              hipStream_t stream)
{
    const float* x    = (const float*)d_in[0];
    const float* Wih1 = (const float*)d_in[1];
    const float* Whh1 = (const float*)d_in[2];
    const float* bih1 = (const float*)d_in[3];
    const float* bhh1 = (const float*)d_in[4];
    const float* Wih2 = (const float*)d_in[5];
    const float* Whh2 = (const float*)d_in[6];
    const float* bih2 = (const float*)d_in[7];
    const float* bhh2 = (const float*)d_in[8];
    const float* W1   = (const float*)d_in[9];
    const float* b1   = (const float*)d_in[10];
    const float* W2   = (const float*)d_in[11];
    const float* b2   = (const float*)d_in[12];
    float* out = (float*)d_out;

    const int B = in_sizes[0] / (T * P);             // 4096
    hipLaunchKernelGGL(lstm2_split, dim3(B / 2), dim3(128), 0, stream,
                       x, Wih1, Whh1, bih1, bhh1, Wih2, Whh2, bih2, bhh2,
                       W1, b1, W2, b2, out);
}